// Round 1
// baseline (299.295 us; speedup 1.0000x reference)
//
#include <hip/hip_runtime.h>
#include <stdint.h>

#define H 768
#define NHEAD 12
#define HDIM 64
#define BATCH 16
#define TSEQ 512
#define BT (BATCH*TSEQ)      // 8192 tokens
#define C3 (3*H)             // 2304

typedef __attribute__((ext_vector_type(8))) short short8;
typedef __attribute__((ext_vector_type(4))) float floatx4;
typedef unsigned short u16;

__device__ __forceinline__ u16 f2bf(float f) {
    union { float f; unsigned int u; } v; v.f = f;
    unsigned int u = v.u;
    return (u16)((u + 0x7FFFu + ((u >> 16) & 1u)) >> 16);
}
__device__ __forceinline__ float bf2f(u16 s) {
    union { unsigned int u; float f; } v; v.u = ((unsigned int)s) << 16;
    return v.f;
}

// async global->LDS, 16B per lane; LDS dest = wave-uniform base + lane*16
__device__ __forceinline__ void async_ld16(const void* g, void* l) {
    __builtin_amdgcn_global_load_lds((__attribute__((address_space(1))) void*)g,
                                     (__attribute__((address_space(3))) void*)l,
                                     16, 0, 0);
}

// ---------------------------------------------------------------------------
// Prep: Wall[2304][768] = [Wq + 2*Bq@Aq ; Wk ; Wv + 2*Bv@Av] as bf16,
//       Wobf[768][768] = Wo bf16, bias_all[2304] fp32.
// ---------------------------------------------------------------------------
__global__ void prep_weights(const float* __restrict__ Wq, const float* __restrict__ bq,
                             const float* __restrict__ Aq, const float* __restrict__ Bq,
                             const float* __restrict__ Wk, const float* __restrict__ bk,
                             const float* __restrict__ Wv, const float* __restrict__ bv,
                             const float* __restrict__ Av, const float* __restrict__ Bv,
                             const float* __restrict__ Wo,
                             u16* __restrict__ Wall, u16* __restrict__ Wobf,
                             float* __restrict__ bias_all)
{
    const int idx = blockIdx.x * 256 + threadIdx.x;   // < 4*H*H
    const int r = idx / H;
    const int c = idx - r * H;
    if (r < H) {
        float v = Wq[idx] + 2.0f * (Bq[r*4+0]*Aq[c] + Bq[r*4+1]*Aq[H+c] +
                                    Bq[r*4+2]*Aq[2*H+c] + Bq[r*4+3]*Aq[3*H+c]);
        Wall[idx] = f2bf(v);
    } else if (r < 2*H) {
        Wall[idx] = f2bf(Wk[idx - H*H]);
    } else if (r < 3*H) {
        const int rr = r - 2*H;
        float v = Wv[rr*H + c] + 2.0f * (Bv[rr*4+0]*Av[c] + Bv[rr*4+1]*Av[H+c] +
                                         Bv[rr*4+2]*Av[2*H+c] + Bv[rr*4+3]*Av[3*H+c]);
        Wall[idx] = f2bf(v);
    } else {
        Wobf[idx - 3*H*H] = f2bf(Wo[idx - 3*H*H]);
    }
    if (idx < C3) {
        bias_all[idx] = (idx < H) ? bq[idx] : (idx < 2*H ? bk[idx - H] : bv[idx - 2*H]);
    }
}

__global__ void cvt_x_kernel(const float* __restrict__ x, u16* __restrict__ xb)
{
    const int i = (blockIdx.x * 256 + threadIdx.x) * 4;
    const float4 v = *(const float4*)(x + i);
    u16 o[4] = { f2bf(v.x), f2bf(v.y), f2bf(v.z), f2bf(v.w) };
    *(uint2*)(xb + i) = *(const uint2*)o;
}

// ---------------------------------------------------------------------------
// GEMM: C[M][N] = A[M][K] * B[N][K]^T + bias[N]   (A,B bf16, acc fp32)
// m97 structure: 128x128 tile, BK=32, global_load_lds w16, 4 waves, 4x4 MFMA
// ---------------------------------------------------------------------------
template<bool OUT_BF16>
__global__ __launch_bounds__(256)
void gemm_bt(const u16* __restrict__ A, const u16* __restrict__ Bw,
             const float* __restrict__ bias, void* __restrict__ Cout,
             int K, int ldc)
{
    __shared__ u16 Ablk[128 * 32];
    __shared__ u16 Bblk[128 * 32];
    const int tid  = threadIdx.x;
    const int wave = tid >> 6;
    const int lane = tid & 63;
    const int quad = lane >> 4;
    const int l16  = lane & 15;
    const int m0 = blockIdx.y * 128;
    const int n0 = blockIdx.x * 128;
    const int mw = (wave & 1) * 64;
    const int nw = (wave >> 1) * 64;

    // staging: wave w covers rows [w*32, w*32+32); lane i -> row w*32+i/4, kcol (i&3)*8
    const int srow = wave * 32 + (lane >> 2);
    const int scol = (lane & 3) * 8;
    const u16* gA = A  + (size_t)(m0 + srow) * K + scol;
    const u16* gB = Bw + (size_t)(n0 + srow) * K + scol;
    u16* lA = Ablk + wave * 32 * 32;
    u16* lB = Bblk + wave * 32 * 32;

    floatx4 acc[4][4] = {};

    for (int k0 = 0; k0 < K; k0 += 32) {
        __syncthreads();
        async_ld16(gA + k0,          lA);
        async_ld16(gA + k0 + 16*K,   lA + 16*32);
        async_ld16(gB + k0,          lB);
        async_ld16(gB + k0 + 16*K,   lB + 16*32);
        __syncthreads();   // vmcnt(0) drain before barrier ensures LDS ready
        short8 af[4], bfr[4];
        #pragma unroll
        for (int mt = 0; mt < 4; mt++)
            af[mt] = *(const short8*)(Ablk + (mw + mt*16 + l16)*32 + quad*8);
        #pragma unroll
        for (int nt = 0; nt < 4; nt++)
            bfr[nt] = *(const short8*)(Bblk + (nw + nt*16 + l16)*32 + quad*8);
        #pragma unroll
        for (int mt = 0; mt < 4; mt++)
            #pragma unroll
            for (int nt = 0; nt < 4; nt++)
                acc[mt][nt] = __builtin_amdgcn_mfma_f32_16x16x32_bf16(af[mt], bfr[nt], acc[mt][nt], 0, 0, 0);
    }

    // epilogue: C layout col=lane&15, row=quad*4+reg
    #pragma unroll
    for (int nt = 0; nt < 4; nt++) {
        const int n = n0 + nw + nt*16 + l16;
        const float bv = bias[n];
        #pragma unroll
        for (int mt = 0; mt < 4; mt++) {
            #pragma unroll
            for (int r = 0; r < 4; r++) {
                const int m = m0 + mw + mt*16 + quad*4 + r;
                const float v = acc[mt][nt][r] + bv;
                if (OUT_BF16) ((u16*)Cout)[(size_t)m * ldc + n] = f2bf(v);
                else          ((float*)Cout)[(size_t)m * ldc + n] = v;
            }
        }
    }
}

// ---------------------------------------------------------------------------
// Attention: one block per (b, h, 32 q-rows). qkv layout [8192][2304] bf16
// (q: 0..767, k: 768..1535, v: 1536..2303). Scores+P in bf16 LDS.
// ---------------------------------------------------------------------------
#define SSTRIDE 520   // 512 + 8 (16B-aligned rows, +4-bank rotation per row)
#define VTSTRIDE 40

__global__ __launch_bounds__(256)
void attn_kernel(const u16* __restrict__ qkv, const int* __restrict__ mask,
                 u16* __restrict__ attn_out)
{
    __shared__ u16  S[32 * SSTRIDE];
    __shared__ u16  Vt[64 * VTSTRIDE];
    __shared__ float invl[32];
    __shared__ float maskadd[512];

    const int qt = blockIdx.x;        // 0..15  (q tile of 32 rows)
    const int bh = blockIdx.y;        // 0..191
    const int b = bh / NHEAD;
    const int h = bh - b * NHEAD;
    const int tid  = threadIdx.x;
    const int wave = tid >> 6;
    const int lane = tid & 63;
    const int quad = lane >> 4;
    const int l16  = lane & 15;

    for (int i = tid; i < TSEQ; i += 256)
        maskadd[i] = (mask[b*TSEQ + i] == 0) ? -1e9f : 0.0f;

    const int qw = (wave >> 1) * 16;      // wave's q-row base within tile
    const size_t base = (size_t)(b * TSEQ) * C3;

    // Q fragments in registers: A[m=lane&15][k=quad*8+j], two K-halves
    short8 qf0, qf1;
    {
        const u16* qp = qkv + base + (size_t)(qt*32 + qw + l16) * C3 + h*HDIM + quad*8;
        qf0 = *(const short8*)qp;
        qf1 = *(const short8*)(qp + 32);
    }
    __syncthreads();

    // ---- phase 1: S = QK^T * scale + mask -> LDS bf16
    for (int t = (wave & 1); t < 32; t += 2) {
        const int key0 = t * 16;
        const u16* kp = qkv + base + (size_t)(key0 + l16) * C3 + H + h*HDIM + quad*8;
        short8 kf0 = *(const short8*)kp;
        short8 kf1 = *(const short8*)(kp + 32);
        floatx4 s = {0.f, 0.f, 0.f, 0.f};
        s = __builtin_amdgcn_mfma_f32_16x16x32_bf16(qf0, kf0, s, 0, 0, 0);
        s = __builtin_amdgcn_mfma_f32_16x16x32_bf16(qf1, kf1, s, 0, 0, 0);
        const float madd = maskadd[key0 + l16];
        #pragma unroll
        for (int r = 0; r < 4; r++) {
            const float val = s[r] * 0.125f + madd;   // 1/sqrt(64)
            S[(qw + quad*4 + r) * SSTRIDE + key0 + l16] = f2bf(val);
        }
    }
    __syncthreads();

    // ---- phase 2: softmax per row (8 threads/row), P stored bf16 in-place
    {
        const int r  = tid >> 3;
        const int s8 = tid & 7;
        u16* row = S + r * SSTRIDE;
        float m = -1e30f;
        for (int c = s8; c < TSEQ; c += 8) m = fmaxf(m, bf2f(row[c]));
        m = fmaxf(m, __shfl_xor(m, 1));
        m = fmaxf(m, __shfl_xor(m, 2));
        m = fmaxf(m, __shfl_xor(m, 4));
        float l = 0.f;
        for (int c = s8; c < TSEQ; c += 8) {
            const float p = __expf(bf2f(row[c]) - m);
            const u16 pb = f2bf(p);
            row[c] = pb;
            l += bf2f(pb);
        }
        l += __shfl_xor(l, 1);
        l += __shfl_xor(l, 2);
        l += __shfl_xor(l, 4);
        if (s8 == 0) invl[r] = 1.0f / l;   // max element gives p=1 => l>=1
    }

    // ---- phase 3: O = P @ V, V transposed through LDS per 32-key chunk
    floatx4 o0 = {0.f,0.f,0.f,0.f}, o1 = {0.f,0.f,0.f,0.f};
    const int dw = (wave & 1) * 32;
    for (int kc = 0; kc < 16; kc++) {
        __syncthreads();
        {
            const int k  = tid >> 3;          // key within chunk 0..31
            const int dg = (tid & 7) * 8;     // d group
            const u16* vp = qkv + base + (size_t)(kc*32 + k) * C3 + 2*H + h*HDIM + dg;
            short8 vv = *(const short8*)vp;
            u16 tmp[8];
            *(short8*)tmp = vv;
            #pragma unroll
            for (int j = 0; j < 8; j++) Vt[(dg + j) * VTSTRIDE + k] = tmp[j];
        }
        __syncthreads();
        short8 pa  = *(const short8*)(S + (qw + l16) * SSTRIDE + kc*32 + quad*8);
        short8 vb0 = *(const short8*)(Vt + (dw + l16) * VTSTRIDE + quad*8);
        short8 vb1 = *(const short8*)(Vt + (dw + 16 + l16) * VTSTRIDE + quad*8);
        o0 = __builtin_amdgcn_mfma_f32_16x16x32_bf16(pa, vb0, o0, 0, 0, 0);
        o1 = __builtin_amdgcn_mfma_f32_16x16x32_bf16(pa, vb1, o1, 0, 0, 0);
    }

    // ---- epilogue: normalize, write attn_out [8192][768] bf16
    #pragma unroll
    for (int r = 0; r < 4; r++) {
        const int q = qw + quad*4 + r;
        const float il = invl[q];
        const size_t orow = (size_t)(b*TSEQ + qt*32 + q) * H + h*HDIM + dw;
        attn_out[orow + l16]      = f2bf(o0[r] * il);
        attn_out[orow + 16 + l16] = f2bf(o1[r] * il);
    }
}

// ---------------------------------------------------------------------------
extern "C" void kernel_launch(void* const* d_in, const int* in_sizes, int n_in,
                              void* d_out, int out_size, void* d_ws, size_t ws_size,
                              hipStream_t stream)
{
    const float* x   = (const float*)d_in[0];
    const int* mask  = (const int*)d_in[1];
    const float* Wq  = (const float*)d_in[2];
    const float* bq  = (const float*)d_in[3];
    const float* Aq  = (const float*)d_in[4];
    const float* Bq  = (const float*)d_in[5];
    const float* Wk  = (const float*)d_in[6];
    const float* bk  = (const float*)d_in[7];
    const float* Wv  = (const float*)d_in[8];
    const float* bv  = (const float*)d_in[9];
    const float* Av  = (const float*)d_in[10];
    const float* Bv  = (const float*)d_in[11];
    const float* Wo  = (const float*)d_in[12];
    const float* bo  = (const float*)d_in[13];

    char* ws = (char*)d_ws;
    u16*   xb      = (u16*)  (ws);                 // 12,582,912 B
    u16*   Wall    = (u16*)  (ws + 12582912);      //  3,538,944 B
    u16*   Wobf    = (u16*)  (ws + 16121856);      //  1,179,648 B
    float* biasall = (float*)(ws + 17301504);      //      9,216 B
    u16*   qkv     = (u16*)  (ws + 17310720);      // 37,748,736 B
    u16*   attn_o  = (u16*)  (ws + 55059456);      // 12,582,912 B  (end 67,642,368)

    prep_weights<<<(4*H*H)/256, 256, 0, stream>>>(Wq, bq, Aq, Bq, Wk, bk, Wv, bv,
                                                  Av, Bv, Wo, Wall, Wobf, biasall);
    cvt_x_kernel<<<(BT*H)/1024, 256, 0, stream>>>(x, xb);
    gemm_bt<true><<<dim3(C3/128, BT/128), 256, 0, stream>>>(xb, Wall, biasall, qkv, H, C3);
    attn_kernel<<<dim3(TSEQ/32, BATCH*NHEAD), 256, 0, stream>>>(qkv, mask, attn_o);
    gemm_bt<false><<<dim3(H/128, BT/128), 256, 0, stream>>>(attn_o, Wobf, bo, d_out, H, H);
}

// Round 2
// 277.371 us; speedup vs baseline: 1.0790x; 1.0790x over previous
//
#include <hip/hip_runtime.h>
#include <stdint.h>

#define H 768
#define NHEAD 12
#define HDIM 64
#define BATCH 16
#define TSEQ 512
#define BT (BATCH*TSEQ)      // 8192 tokens
#define C3 (3*H)             // 2304

typedef __attribute__((ext_vector_type(8))) short short8;
typedef __attribute__((ext_vector_type(4))) float floatx4;
typedef unsigned short u16;

__device__ __forceinline__ u16 f2bf(float f) {
    union { float f; unsigned int u; } v; v.f = f;
    unsigned int u = v.u;
    return (u16)((u + 0x7FFFu + ((u >> 16) & 1u)) >> 16);
}
__device__ __forceinline__ float bf2f(u16 s) {
    union { unsigned int u; float f; } v; v.u = ((unsigned int)s) << 16;
    return v.f;
}

// async global->LDS, 16B per lane; LDS dest = wave-uniform base + lane*16
__device__ __forceinline__ void async_ld16(const void* g, void* l) {
    __builtin_amdgcn_global_load_lds((__attribute__((address_space(1))) void*)g,
                                     (__attribute__((address_space(3))) void*)l,
                                     16, 0, 0);
}

// ---------------------------------------------------------------------------
// Prep: Wall[2304][768] = [Wq + 2*Bq@Aq ; Wk ; Wv + 2*Bv@Av] as bf16,
//       Wobf[768][768] = Wo bf16, bias_all[2304] fp32.
// ---------------------------------------------------------------------------
__global__ void prep_weights(const float* __restrict__ Wq, const float* __restrict__ bq,
                             const float* __restrict__ Aq, const float* __restrict__ Bq,
                             const float* __restrict__ Wk, const float* __restrict__ bk,
                             const float* __restrict__ Wv, const float* __restrict__ bv,
                             const float* __restrict__ Av, const float* __restrict__ Bv,
                             const float* __restrict__ Wo,
                             u16* __restrict__ Wall, u16* __restrict__ Wobf,
                             float* __restrict__ bias_all)
{
    const int idx = blockIdx.x * 256 + threadIdx.x;   // < 4*H*H
    const int r = idx / H;
    const int c = idx - r * H;
    if (r < H) {
        float v = Wq[idx] + 2.0f * (Bq[r*4+0]*Aq[c] + Bq[r*4+1]*Aq[H+c] +
                                    Bq[r*4+2]*Aq[2*H+c] + Bq[r*4+3]*Aq[3*H+c]);
        Wall[idx] = f2bf(v);
    } else if (r < 2*H) {
        Wall[idx] = f2bf(Wk[idx - H*H]);
    } else if (r < 3*H) {
        const int rr = r - 2*H;
        float v = Wv[rr*H + c] + 2.0f * (Bv[rr*4+0]*Av[c] + Bv[rr*4+1]*Av[H+c] +
                                         Bv[rr*4+2]*Av[2*H+c] + Bv[rr*4+3]*Av[3*H+c]);
        Wall[idx] = f2bf(v);
    } else {
        Wobf[idx - 3*H*H] = f2bf(Wo[idx - 3*H*H]);
    }
    if (idx < C3) {
        bias_all[idx] = (idx < H) ? bq[idx] : (idx < 2*H ? bk[idx - H] : bv[idx - 2*H]);
    }
}

__global__ void cvt_x_kernel(const float* __restrict__ x, u16* __restrict__ xb)
{
    const int i = (blockIdx.x * 256 + threadIdx.x) * 4;
    const float4 v = *(const float4*)(x + i);
    u16 o[4] = { f2bf(v.x), f2bf(v.y), f2bf(v.z), f2bf(v.w) };
    *(uint2*)(xb + i) = *(const uint2*)o;
}

// ---------------------------------------------------------------------------
// GEMM: C[M][N] = A[M][K] * B[N][K]^T + bias[N]   (A,B bf16, acc fp32)
// m97 structure: 128x128 tile, BK=32, global_load_lds w16, 4 waves, 4x4 MFMA
// ---------------------------------------------------------------------------
template<bool OUT_BF16>
__global__ __launch_bounds__(256)
void gemm_bt(const u16* __restrict__ A, const u16* __restrict__ Bw,
             const float* __restrict__ bias, void* __restrict__ Cout,
             int K, int ldc)
{
    __shared__ u16 Ablk[128 * 32];
    __shared__ u16 Bblk[128 * 32];
    const int tid  = threadIdx.x;
    const int wave = tid >> 6;
    const int lane = tid & 63;
    const int quad = lane >> 4;
    const int l16  = lane & 15;
    const int m0 = blockIdx.y * 128;
    const int n0 = blockIdx.x * 128;
    const int mw = (wave & 1) * 64;
    const int nw = (wave >> 1) * 64;

    const int srow = wave * 32 + (lane >> 2);
    const int scol = (lane & 3) * 8;
    const u16* gA = A  + (size_t)(m0 + srow) * K + scol;
    const u16* gB = Bw + (size_t)(n0 + srow) * K + scol;
    u16* lA = Ablk + wave * 32 * 32;
    u16* lB = Bblk + wave * 32 * 32;

    floatx4 acc[4][4] = {};

    for (int k0 = 0; k0 < K; k0 += 32) {
        __syncthreads();
        async_ld16(gA + k0,          lA);
        async_ld16(gA + k0 + 16*K,   lA + 16*32);
        async_ld16(gB + k0,          lB);
        async_ld16(gB + k0 + 16*K,   lB + 16*32);
        __syncthreads();
        short8 af[4], bfr[4];
        #pragma unroll
        for (int mt = 0; mt < 4; mt++)
            af[mt] = *(const short8*)(Ablk + (mw + mt*16 + l16)*32 + quad*8);
        #pragma unroll
        for (int nt = 0; nt < 4; nt++)
            bfr[nt] = *(const short8*)(Bblk + (nw + nt*16 + l16)*32 + quad*8);
        #pragma unroll
        for (int mt = 0; mt < 4; mt++)
            #pragma unroll
            for (int nt = 0; nt < 4; nt++)
                acc[mt][nt] = __builtin_amdgcn_mfma_f32_16x16x32_bf16(af[mt], bfr[nt], acc[mt][nt], 0, 0, 0);
    }

    #pragma unroll
    for (int nt = 0; nt < 4; nt++) {
        const int n = n0 + nw + nt*16 + l16;
        const float bv = bias[n];
        #pragma unroll
        for (int mt = 0; mt < 4; mt++) {
            #pragma unroll
            for (int r = 0; r < 4; r++) {
                const int m = m0 + mw + mt*16 + quad*4 + r;
                const float v = acc[mt][nt][r] + bv;
                if (OUT_BF16) ((u16*)Cout)[(size_t)m * ldc + n] = f2bf(v);
                else          ((float*)Cout)[(size_t)m * ldc + n] = v;
            }
        }
    }
}

// ---------------------------------------------------------------------------
// V transpose: vt[bh][d][t] <- qkv[b*512+t][2H + h*64 + d]   (bf16)
// ---------------------------------------------------------------------------
#define TSTRIDE 72   // u16; 144 B rows (16B-aligned, conflict-free writes)
__global__ __launch_bounds__(256)
void vtrans_kernel(const u16* __restrict__ qkv, u16* __restrict__ vt)
{
    __shared__ u16 Lt[64 * TSTRIDE];
    const int tc = blockIdx.x;        // token chunk of 64
    const int bh = blockIdx.y;
    const int b = bh / NHEAD, h = bh - b * NHEAD;
    const int tid = threadIdx.x;

    // phase A: read 64 tokens x 64 d; thread: token=tid&63, d-group=(tid>>6)*16
    {
        const int tok = tid & 63;
        const int dg  = (tid >> 6) * 16;
        const u16* p = qkv + (size_t)(b*TSEQ + tc*64 + tok) * C3 + 2*H + h*HDIM + dg;
        u16 tmp[16];
        *(short8*)tmp       = *(const short8*)p;
        *(short8*)(tmp + 8) = *(const short8*)(p + 8);
        #pragma unroll
        for (int j = 0; j < 16; j++) Lt[(dg + j) * TSTRIDE + tok] = tmp[j];
    }
    __syncthreads();
    // phase B: thread: d=tid>>2, tseg=(tid&3)*16 -> 2x b128 LDS read, 32B global write
    {
        const int d  = tid >> 2;
        const int ts = (tid & 3) * 16;
        uint4 a0 = *(const uint4*)(Lt + d * TSTRIDE + ts);
        uint4 a1 = *(const uint4*)(Lt + d * TSTRIDE + ts + 8);
        u16* op = vt + ((size_t)bh * HDIM + d) * TSEQ + tc*64 + ts;
        *(uint4*)op       = a0;
        *(uint4*)(op + 8) = a1;
    }
}

// ---------------------------------------------------------------------------
// Attention v2: wave-independent, no-max softmax, V^T from global.
// One block = (b,h, 64 q rows); each wave owns 16 q rows end-to-end.
// ---------------------------------------------------------------------------
#define PSTRIDE 40   // u16; 80 B rows: 16B-aligned b128 reads, 2-way-free writes

__global__ __launch_bounds__(256)
void attn_kernel(const u16* __restrict__ qkv, const u16* __restrict__ vt,
                 const int* __restrict__ mask, u16* __restrict__ attn_out)
{
    __shared__ float maskadd[TSEQ];
    __shared__ u16 Pbuf[4][16 * PSTRIDE];

    const int qt = blockIdx.x;        // 0..7 (64 q rows)
    const int bh = blockIdx.y;        // 0..191
    const int b = bh / NHEAD, h = bh - b * NHEAD;
    const int tid  = threadIdx.x;
    const int wave = tid >> 6;
    const int lane = tid & 63;
    const int quad = lane >> 4;
    const int l16  = lane & 15;

    for (int i = tid; i < TSEQ; i += 256)
        maskadd[i] = (mask[b*TSEQ + i] == 0) ? -1e9f : 0.0f;
    __syncthreads();   // the only block-wide barrier

    const size_t btok = (size_t)b * TSEQ;
    const int q0 = qt * 64 + wave * 16;

    // Q fragments: A[m=l16][k=quad*8+j], two K-halves of HDIM=64
    const u16* qp = qkv + (btok + q0 + l16) * C3 + h*HDIM + quad*8;
    const short8 qf0 = *(const short8*)qp;
    const short8 qf1 = *(const short8*)(qp + 32);

    const u16* kbase = qkv + btok * C3 + H + h*HDIM + quad*8;
    const u16* vbase = vt + (size_t)bh * HDIM * TSEQ + quad*8;
    u16* Pw = Pbuf[wave];

    floatx4 o[4] = {};                 // 16q x 64d accumulator, C-layout
    float lsum[4] = {0.f, 0.f, 0.f, 0.f};

    for (int kb = 0; kb < TSEQ; kb += 32) {
        // QK^T for 32 keys (two 16-key tiles)
        const u16* kp0 = kbase + (size_t)(kb + l16) * C3;
        const u16* kp1 = kbase + (size_t)(kb + 16 + l16) * C3;
        const short8 k00 = *(const short8*)kp0, k01 = *(const short8*)(kp0 + 32);
        const short8 k10 = *(const short8*)kp1, k11 = *(const short8*)(kp1 + 32);
        floatx4 s0 = {0.f,0.f,0.f,0.f}, s1 = {0.f,0.f,0.f,0.f};
        s0 = __builtin_amdgcn_mfma_f32_16x16x32_bf16(qf0, k00, s0, 0, 0, 0);
        s0 = __builtin_amdgcn_mfma_f32_16x16x32_bf16(qf1, k01, s0, 0, 0, 0);
        s1 = __builtin_amdgcn_mfma_f32_16x16x32_bf16(qf0, k10, s1, 0, 0, 0);
        s1 = __builtin_amdgcn_mfma_f32_16x16x32_bf16(qf1, k11, s1, 0, 0, 0);

        // p = exp(s/8 + maskadd); no max pass (scores are O(1), masked -> 0)
        const float m0 = maskadd[kb + l16];
        const float m1 = maskadd[kb + 16 + l16];
        #pragma unroll
        for (int r = 0; r < 4; r++) {
            const float p0 = __expf(s0[r] * 0.125f + m0);
            const float p1 = __expf(s1[r] * 0.125f + m1);
            lsum[r] += p0 + p1;
            Pw[(quad*4 + r) * PSTRIDE + l16]      = f2bf(p0);
            Pw[(quad*4 + r) * PSTRIDE + 16 + l16] = f2bf(p1);
        }

        // C->A layout flip through per-wave LDS (DS in-order per wave: no barrier)
        const short8 pa = *(const short8*)(Pw + l16 * PSTRIDE + quad*8);

        // PV: V^T fragments straight from global (coalesced 16B)
        #pragma unroll
        for (int d = 0; d < 4; d++) {
            const short8 vb = *(const short8*)(vbase + (size_t)(d*16 + l16) * TSEQ + kb);
            o[d] = __builtin_amdgcn_mfma_f32_16x16x32_bf16(pa, vb, o[d], 0, 0, 0);
        }
    }

    // row sums: reduce over l16 lanes (bits 0..3)
    float inv[4];
    #pragma unroll
    for (int r = 0; r < 4; r++) {
        float l = lsum[r];
        l += __shfl_xor(l, 1);
        l += __shfl_xor(l, 2);
        l += __shfl_xor(l, 4);
        l += __shfl_xor(l, 8);
        inv[r] = 1.0f / l;
    }

    #pragma unroll
    for (int d = 0; d < 4; d++) {
        #pragma unroll
        for (int r = 0; r < 4; r++) {
            const int q = q0 + quad*4 + r;
            attn_out[(btok + q) * H + h*HDIM + d*16 + l16] = f2bf(o[d][r] * inv[r]);
        }
    }
}

// ---------------------------------------------------------------------------
extern "C" void kernel_launch(void* const* d_in, const int* in_sizes, int n_in,
                              void* d_out, int out_size, void* d_ws, size_t ws_size,
                              hipStream_t stream)
{
    const float* x   = (const float*)d_in[0];
    const int* mask  = (const int*)d_in[1];
    const float* Wq  = (const float*)d_in[2];
    const float* bq  = (const float*)d_in[3];
    const float* Aq  = (const float*)d_in[4];
    const float* Bq  = (const float*)d_in[5];
    const float* Wk  = (const float*)d_in[6];
    const float* bk  = (const float*)d_in[7];
    const float* Wv  = (const float*)d_in[8];
    const float* bv  = (const float*)d_in[9];
    const float* Av  = (const float*)d_in[10];
    const float* Bv  = (const float*)d_in[11];
    const float* Wo  = (const float*)d_in[12];
    const float* bo  = (const float*)d_in[13];

    char* ws = (char*)d_ws;
    u16*   xb      = (u16*)  (ws);                 // 12,582,912 B (reused as vt)
    u16*   Wall    = (u16*)  (ws + 12582912);      //  3,538,944 B
    u16*   Wobf    = (u16*)  (ws + 16121856);      //  1,179,648 B
    float* biasall = (float*)(ws + 17301504);      //      9,216 B
    u16*   qkv     = (u16*)  (ws + 17310720);      // 37,748,736 B
    u16*   attn_o  = (u16*)  (ws + 55059456);      // 12,582,912 B  (end 67,642,368)
    u16*   vt      = xb;     // xb is dead after the QKV GEMM; reuse for V^T

    prep_weights<<<(4*H*H)/256, 256, 0, stream>>>(Wq, bq, Aq, Bq, Wk, bk, Wv, bv,
                                                  Av, Bv, Wo, Wall, Wobf, biasall);
    cvt_x_kernel<<<(BT*H)/1024, 256, 0, stream>>>(x, xb);
    gemm_bt<true><<<dim3(C3/128, BT/128), 256, 0, stream>>>(xb, Wall, biasall, qkv, H, C3);
    vtrans_kernel<<<dim3(TSEQ/64, BATCH*NHEAD), 256, 0, stream>>>(qkv, vt);
    attn_kernel<<<dim3(TSEQ/64, BATCH*NHEAD), 256, 0, stream>>>(qkv, vt, mask, attn_o);
    gemm_bt<false><<<dim3(H/128, BT/128), 256, 0, stream>>>(attn_o, Wobf, bo, d_out, H, H);
}

// Round 3
// 240.705 us; speedup vs baseline: 1.2434x; 1.1523x over previous
//
#include <hip/hip_runtime.h>
#include <stdint.h>

#define H 768
#define NHEAD 12
#define HDIM 64
#define BATCH 16
#define TSEQ 512
#define BT (BATCH*TSEQ)      // 8192 tokens
#define C3 (3*H)             // 2304

typedef __attribute__((ext_vector_type(8))) short short8;
typedef __attribute__((ext_vector_type(4))) float floatx4;
typedef unsigned short u16;

__device__ __forceinline__ u16 f2bf(float f) {
    union { float f; unsigned int u; } v; v.f = f;
    unsigned int u = v.u;
    return (u16)((u + 0x7FFFu + ((u >> 16) & 1u)) >> 16);
}
__device__ __forceinline__ float bf2f(u16 s) {
    union { unsigned int u; float f; } v; v.u = ((unsigned int)s) << 16;
    return v.f;
}

// async global->LDS, 16B per lane; LDS dest = wave-uniform base + lane*16
__device__ __forceinline__ void async_ld16(const void* g, void* l) {
    __builtin_amdgcn_global_load_lds((__attribute__((address_space(1))) void*)g,
                                     (__attribute__((address_space(3))) void*)l,
                                     16, 0, 0);
}

// ---------------------------------------------------------------------------
// Prep: Wall[2304][768] = [Wq + 2*Bq@Aq ; Wk ; Wv + 2*Bv@Av] as bf16,
//       Wobf[768][768] = Wo bf16, bias_all[2304] fp32.
// ---------------------------------------------------------------------------
__global__ void prep_weights(const float* __restrict__ Wq, const float* __restrict__ bq,
                             const float* __restrict__ Aq, const float* __restrict__ Bq,
                             const float* __restrict__ Wk, const float* __restrict__ bk,
                             const float* __restrict__ Wv, const float* __restrict__ bv,
                             const float* __restrict__ Av, const float* __restrict__ Bv,
                             const float* __restrict__ Wo,
                             u16* __restrict__ Wall, u16* __restrict__ Wobf,
                             float* __restrict__ bias_all)
{
    const int idx = blockIdx.x * 256 + threadIdx.x;   // < 4*H*H
    const int r = idx / H;
    const int c = idx - r * H;
    if (r < H) {
        float v = Wq[idx] + 2.0f * (Bq[r*4+0]*Aq[c] + Bq[r*4+1]*Aq[H+c] +
                                    Bq[r*4+2]*Aq[2*H+c] + Bq[r*4+3]*Aq[3*H+c]);
        Wall[idx] = f2bf(v);
    } else if (r < 2*H) {
        Wall[idx] = f2bf(Wk[idx - H*H]);
    } else if (r < 3*H) {
        const int rr = r - 2*H;
        float v = Wv[rr*H + c] + 2.0f * (Bv[rr*4+0]*Av[c] + Bv[rr*4+1]*Av[H+c] +
                                         Bv[rr*4+2]*Av[2*H+c] + Bv[rr*4+3]*Av[3*H+c]);
        Wall[idx] = f2bf(v);
    } else {
        Wobf[idx - 3*H*H] = f2bf(Wo[idx - 3*H*H]);
    }
    if (idx < C3) {
        bias_all[idx] = (idx < H) ? bq[idx] : (idx < 2*H ? bk[idx - H] : bv[idx - 2*H]);
    }
}

__global__ void cvt_x_kernel(const float* __restrict__ x, u16* __restrict__ xb)
{
    const int i = (blockIdx.x * 256 + threadIdx.x) * 4;
    const float4 v = *(const float4*)(x + i);
    u16 o[4] = { f2bf(v.x), f2bf(v.y), f2bf(v.z), f2bf(v.w) };
    *(uint2*)(xb + i) = *(const uint2*)o;
}

// ---------------------------------------------------------------------------
// GEMM: C[M][N] = A[M][K] * B[N][K]^T + bias[N]   (A,B bf16, acc fp32)
// m97 structure: 128x128 tile, BK=32, global_load_lds w16, 4 waves, 4x4 MFMA
// ---------------------------------------------------------------------------
template<bool OUT_BF16>
__global__ __launch_bounds__(256)
void gemm_bt(const u16* __restrict__ A, const u16* __restrict__ Bw,
             const float* __restrict__ bias, void* __restrict__ Cout,
             int K, int ldc)
{
    __shared__ u16 Ablk[128 * 32];
    __shared__ u16 Bblk[128 * 32];
    const int tid  = threadIdx.x;
    const int wave = tid >> 6;
    const int lane = tid & 63;
    const int quad = lane >> 4;
    const int l16  = lane & 15;
    const int m0 = blockIdx.y * 128;
    const int n0 = blockIdx.x * 128;
    const int mw = (wave & 1) * 64;
    const int nw = (wave >> 1) * 64;

    const int srow = wave * 32 + (lane >> 2);
    const int scol = (lane & 3) * 8;
    const u16* gA = A  + (size_t)(m0 + srow) * K + scol;
    const u16* gB = Bw + (size_t)(n0 + srow) * K + scol;
    u16* lA = Ablk + wave * 32 * 32;
    u16* lB = Bblk + wave * 32 * 32;

    floatx4 acc[4][4] = {};

    for (int k0 = 0; k0 < K; k0 += 32) {
        __syncthreads();
        async_ld16(gA + k0,          lA);
        async_ld16(gA + k0 + 16*K,   lA + 16*32);
        async_ld16(gB + k0,          lB);
        async_ld16(gB + k0 + 16*K,   lB + 16*32);
        __syncthreads();
        short8 af[4], bfr[4];
        #pragma unroll
        for (int mt = 0; mt < 4; mt++)
            af[mt] = *(const short8*)(Ablk + (mw + mt*16 + l16)*32 + quad*8);
        #pragma unroll
        for (int nt = 0; nt < 4; nt++)
            bfr[nt] = *(const short8*)(Bblk + (nw + nt*16 + l16)*32 + quad*8);
        #pragma unroll
        for (int mt = 0; mt < 4; mt++)
            #pragma unroll
            for (int nt = 0; nt < 4; nt++)
                acc[mt][nt] = __builtin_amdgcn_mfma_f32_16x16x32_bf16(af[mt], bfr[nt], acc[mt][nt], 0, 0, 0);
    }

    #pragma unroll
    for (int nt = 0; nt < 4; nt++) {
        const int n = n0 + nw + nt*16 + l16;
        const float bv = bias[n];
        #pragma unroll
        for (int mt = 0; mt < 4; mt++) {
            #pragma unroll
            for (int r = 0; r < 4; r++) {
                const int m = m0 + mw + mt*16 + quad*4 + r;
                const float v = acc[mt][nt][r] + bv;
                if (OUT_BF16) ((u16*)Cout)[(size_t)m * ldc + n] = f2bf(v);
                else          ((float*)Cout)[(size_t)m * ldc + n] = v;
            }
        }
    }
}

// ---------------------------------------------------------------------------
// V transpose: vt[bh][d][t] <- qkv[b*512+t][2H + h*64 + d]   (bf16)
// ---------------------------------------------------------------------------
#define TSTRIDE 72   // u16; 144 B rows (16B-aligned, conflict-free writes)
__global__ __launch_bounds__(256)
void vtrans_kernel(const u16* __restrict__ qkv, u16* __restrict__ vt)
{
    __shared__ u16 Lt[64 * TSTRIDE];
    const int tc = blockIdx.x;        // token chunk of 64
    const int bh = blockIdx.y;
    const int b = bh / NHEAD, h = bh - b * NHEAD;
    const int tid = threadIdx.x;

    {
        const int tok = tid & 63;
        const int dg  = (tid >> 6) * 16;
        const u16* p = qkv + (size_t)(b*TSEQ + tc*64 + tok) * C3 + 2*H + h*HDIM + dg;
        u16 tmp[16];
        *(short8*)tmp       = *(const short8*)p;
        *(short8*)(tmp + 8) = *(const short8*)(p + 8);
        #pragma unroll
        for (int j = 0; j < 16; j++) Lt[(dg + j) * TSTRIDE + tok] = tmp[j];
    }
    __syncthreads();
    {
        const int d  = tid >> 2;
        const int ts = (tid & 3) * 16;
        uint4 a0 = *(const uint4*)(Lt + d * TSTRIDE + ts);
        uint4 a1 = *(const uint4*)(Lt + d * TSTRIDE + ts + 8);
        u16* op = vt + ((size_t)bh * HDIM + d) * TSEQ + tc*64 + ts;
        *(uint4*)op       = a0;
        *(uint4*)(op + 8) = a1;
    }
}

// ---------------------------------------------------------------------------
// Attention v3: wave-independent, 32 q-rows/wave, explicit K/V register
// ping-pong double-buffering to hide global latency (round-2 profile showed
// pure latency-bound: all pipes <20% busy, VGPR_Count=40 = no pipelining).
// ---------------------------------------------------------------------------
#define PSTRIDE 40   // u16; 80 B rows: 16B-aligned b128 reads, 2-way-free writes

__global__ __launch_bounds__(256, 3)
void attn_kernel(const u16* __restrict__ qkv, const u16* __restrict__ vt,
                 const int* __restrict__ mask, u16* __restrict__ attn_out)
{
    __shared__ float maskadd[TSEQ];
    __shared__ u16 Pbuf[4][2][16 * PSTRIDE];

    const int qt = blockIdx.x;        // 0..3 (128 q rows per block)
    const int bh = blockIdx.y;        // 0..191
    const int b = bh / NHEAD, h = bh - b * NHEAD;
    const int tid  = threadIdx.x;
    const int wave = tid >> 6;
    const int lane = tid & 63;
    const int quad = lane >> 4;
    const int l16  = lane & 15;

    for (int i = tid; i < TSEQ; i += 256)
        maskadd[i] = (mask[b*TSEQ + i] == 0) ? -1e9f : 0.0f;
    __syncthreads();   // the only block-wide barrier

    const size_t btok = (size_t)b * TSEQ;
    const int q0 = qt * 128 + wave * 32;

    // Q fragments for 2 row-tiles: A[m=l16][k=quad*8+j], two K-halves of HDIM
    short8 qf[2][2];
    #pragma unroll
    for (int m = 0; m < 2; m++) {
        const u16* qp = qkv + (btok + q0 + m*16 + l16) * C3 + h*HDIM + quad*8;
        qf[m][0] = *(const short8*)qp;
        qf[m][1] = *(const short8*)(qp + 32);
    }

    const u16* kbase = qkv + btok * C3 + H + h*HDIM + quad*8;
    const u16* vbase = vt + (size_t)bh * HDIM * TSEQ + quad*8;

    floatx4 o[2][4] = {};              // 2 x (16q x 64d), C-layout
    float lsum[2][4] = {};

    // 32-key block load: K = 2 subtiles x 2 d-halves, V^T = 4 d-tiles
    auto loadKV = [&](int kb, short8* kf, short8* vf) {
        const u16* kp0 = kbase + (size_t)(kb + l16) * C3;
        const u16* kp1 = kbase + (size_t)(kb + 16 + l16) * C3;
        kf[0] = *(const short8*)kp0;
        kf[1] = *(const short8*)(kp0 + 32);
        kf[2] = *(const short8*)kp1;
        kf[3] = *(const short8*)(kp1 + 32);
        #pragma unroll
        for (int d = 0; d < 4; d++)
            vf[d] = *(const short8*)(vbase + (size_t)(d*16 + l16) * TSEQ + kb);
    };

    auto compute = [&](int kb, const short8* kf, const short8* vf) {
        floatx4 s[2][2];
        #pragma unroll
        for (int m = 0; m < 2; m++)
            #pragma unroll
            for (int t = 0; t < 2; t++) {
                floatx4 acc = {0.f, 0.f, 0.f, 0.f};
                acc = __builtin_amdgcn_mfma_f32_16x16x32_bf16(qf[m][0], kf[t*2+0], acc, 0, 0, 0);
                acc = __builtin_amdgcn_mfma_f32_16x16x32_bf16(qf[m][1], kf[t*2+1], acc, 0, 0, 0);
                s[m][t] = acc;
            }
        const float m0 = maskadd[kb + l16];
        const float m1 = maskadd[kb + 16 + l16];
        #pragma unroll
        for (int m = 0; m < 2; m++) {
            u16* Pw = Pbuf[wave][m];
            #pragma unroll
            for (int r = 0; r < 4; r++) {
                const float p0 = __expf(s[m][0][r] * 0.125f + m0);
                const float p1 = __expf(s[m][1][r] * 0.125f + m1);
                lsum[m][r] += p0 + p1;
                Pw[(quad*4 + r) * PSTRIDE + l16]      = f2bf(p0);
                Pw[(quad*4 + r) * PSTRIDE + 16 + l16] = f2bf(p1);
            }
        }
        // C->A flip via per-wave LDS (DS in-order within a wave: no barrier)
        #pragma unroll
        for (int m = 0; m < 2; m++) {
            const short8 pa = *(const short8*)(Pbuf[wave][m] + l16 * PSTRIDE + quad*8);
            #pragma unroll
            for (int d = 0; d < 4; d++)
                o[m][d] = __builtin_amdgcn_mfma_f32_16x16x32_bf16(pa, vf[d], o[m][d], 0, 0, 0);
        }
    };

    short8 kA[4], vA[4], kB[4], vB[4];
    loadKV(0, kA, vA);
    for (int kb = 0; kb < TSEQ - 64; kb += 64) {
        loadKV(kb + 32, kB, vB);       // prefetch while computing on A
        compute(kb, kA, vA);
        loadKV(kb + 64, kA, vA);       // prefetch while computing on B
        compute(kb + 32, kB, vB);
    }
    loadKV(TSEQ - 32, kB, vB);
    compute(TSEQ - 64, kA, vA);
    compute(TSEQ - 32, kB, vB);

    // row sums: reduce over l16 lanes (bits 0..3 of lane)
    #pragma unroll
    for (int m = 0; m < 2; m++) {
        float inv[4];
        #pragma unroll
        for (int r = 0; r < 4; r++) {
            float l = lsum[m][r];
            l += __shfl_xor(l, 1);
            l += __shfl_xor(l, 2);
            l += __shfl_xor(l, 4);
            l += __shfl_xor(l, 8);
            inv[r] = 1.0f / l;
        }
        #pragma unroll
        for (int d = 0; d < 4; d++)
            #pragma unroll
            for (int r = 0; r < 4; r++) {
                const int q = q0 + m*16 + quad*4 + r;
                attn_out[(btok + q) * H + h*HDIM + d*16 + l16] = f2bf(o[m][d][r] * inv[r]);
            }
    }
}

// ---------------------------------------------------------------------------
extern "C" void kernel_launch(void* const* d_in, const int* in_sizes, int n_in,
                              void* d_out, int out_size, void* d_ws, size_t ws_size,
                              hipStream_t stream)
{
    const float* x   = (const float*)d_in[0];
    const int* mask  = (const int*)d_in[1];
    const float* Wq  = (const float*)d_in[2];
    const float* bq  = (const float*)d_in[3];
    const float* Aq  = (const float*)d_in[4];
    const float* Bq  = (const float*)d_in[5];
    const float* Wk  = (const float*)d_in[6];
    const float* bk  = (const float*)d_in[7];
    const float* Wv  = (const float*)d_in[8];
    const float* bv  = (const float*)d_in[9];
    const float* Av  = (const float*)d_in[10];
    const float* Bv  = (const float*)d_in[11];
    const float* Wo  = (const float*)d_in[12];
    const float* bo  = (const float*)d_in[13];

    char* ws = (char*)d_ws;
    u16*   xb      = (u16*)  (ws);                 // 12,582,912 B (reused as vt)
    u16*   Wall    = (u16*)  (ws + 12582912);      //  3,538,944 B
    u16*   Wobf    = (u16*)  (ws + 16121856);      //  1,179,648 B
    float* biasall = (float*)(ws + 17301504);      //      9,216 B
    u16*   qkv     = (u16*)  (ws + 17310720);      // 37,748,736 B
    u16*   attn_o  = (u16*)  (ws + 55059456);      // 12,582,912 B  (end 67,642,368)
    u16*   vt      = xb;     // xb is dead after the QKV GEMM; reuse for V^T

    prep_weights<<<(4*H*H)/256, 256, 0, stream>>>(Wq, bq, Aq, Bq, Wk, bk, Wv, bv,
                                                  Av, Bv, Wo, Wall, Wobf, biasall);
    cvt_x_kernel<<<(BT*H)/1024, 256, 0, stream>>>(x, xb);
    gemm_bt<true><<<dim3(C3/128, BT/128), 256, 0, stream>>>(xb, Wall, biasall, qkv, H, C3);
    vtrans_kernel<<<dim3(TSEQ/64, BATCH*NHEAD), 256, 0, stream>>>(qkv, vt);
    attn_kernel<<<dim3(TSEQ/128, BATCH*NHEAD), 256, 0, stream>>>(qkv, vt, mask, attn_o);
    gemm_bt<false><<<dim3(H/128, BT/128), 256, 0, stream>>>(attn_o, Wobf, bo, d_out, H, H);
}

// Round 4
// 228.526 us; speedup vs baseline: 1.3097x; 1.0533x over previous
//
#include <hip/hip_runtime.h>
#include <stdint.h>

#define H 768
#define NHEAD 12
#define HDIM 64
#define BATCH 16
#define TSEQ 512
#define BT (BATCH*TSEQ)      // 8192 tokens
#define C3 (3*H)             // 2304
#define LDQK 1536            // packed Q,K row stride

typedef __attribute__((ext_vector_type(8))) short short8;
typedef __attribute__((ext_vector_type(4))) float floatx4;
typedef unsigned short u16;

__device__ __forceinline__ u16 f2bf(float f) {
    union { float f; unsigned int u; } v; v.f = f;
    unsigned int u = v.u;
    return (u16)((u + 0x7FFFu + ((u >> 16) & 1u)) >> 16);
}

// async global->LDS, 16B per lane; LDS dest = wave-uniform base + lane*16
__device__ __forceinline__ void async_ld16(const void* g, void* l) {
    __builtin_amdgcn_global_load_lds((__attribute__((address_space(1))) void*)g,
                                     (__attribute__((address_space(3))) void*)l,
                                     16, 0, 0);
}

// ---------------------------------------------------------------------------
// Prep: Wall[2304][768] = [Wq + 2*Bq@Aq ; Wk ; Wv + 2*Bv@Av] as bf16,
//       Wobf[768][768] = Wo bf16, bias_all[2304] fp32.
// ---------------------------------------------------------------------------
__global__ void prep_weights(const float* __restrict__ Wq, const float* __restrict__ bq,
                             const float* __restrict__ Aq, const float* __restrict__ Bq,
                             const float* __restrict__ Wk, const float* __restrict__ bk,
                             const float* __restrict__ Wv, const float* __restrict__ bv,
                             const float* __restrict__ Av, const float* __restrict__ Bv,
                             const float* __restrict__ Wo,
                             u16* __restrict__ Wall, u16* __restrict__ Wobf,
                             float* __restrict__ bias_all)
{
    const int idx = blockIdx.x * 256 + threadIdx.x;   // < 4*H*H
    const int r = idx / H;
    const int c = idx - r * H;
    if (r < H) {
        float v = Wq[idx] + 2.0f * (Bq[r*4+0]*Aq[c] + Bq[r*4+1]*Aq[H+c] +
                                    Bq[r*4+2]*Aq[2*H+c] + Bq[r*4+3]*Aq[3*H+c]);
        Wall[idx] = f2bf(v);
    } else if (r < 2*H) {
        Wall[idx] = f2bf(Wk[idx - H*H]);
    } else if (r < 3*H) {
        const int rr = r - 2*H;
        float v = Wv[rr*H + c] + 2.0f * (Bv[rr*4+0]*Av[c] + Bv[rr*4+1]*Av[H+c] +
                                         Bv[rr*4+2]*Av[2*H+c] + Bv[rr*4+3]*Av[3*H+c]);
        Wall[idx] = f2bf(v);
    } else {
        Wobf[idx - 3*H*H] = f2bf(Wo[idx - 3*H*H]);
    }
    if (idx < C3) {
        bias_all[idx] = (idx < H) ? bq[idx] : (idx < 2*H ? bk[idx - H] : bv[idx - 2*H]);
    }
}

__global__ void cvt_x_kernel(const float* __restrict__ x, u16* __restrict__ xb)
{
    const int i = (blockIdx.x * 256 + threadIdx.x) * 4;
    const float4 v = *(const float4*)(x + i);
    u16 o[4] = { f2bf(v.x), f2bf(v.y), f2bf(v.z), f2bf(v.w) };
    *(uint2*)(xb + i) = *(const uint2*)o;
}

// ---------------------------------------------------------------------------
// GEMM: C[M][N] = A[M][K] * B[N][K]^T + bias[N]   (A,B bf16, acc fp32)
// BK=64, XOR-swizzled LDS (conflict-free b128 reads), global_load_lds w16.
// MODE 0: fp32 out, ldc=H.
// MODE 1: QKV — n<1536 -> bf16 qk[m][n] (ldc=1536); n>=1536 -> V transposed
//         into vt[bh][d][t] with packed 4xbf16 stores (t = m&511).
// ---------------------------------------------------------------------------
template<int MODE>
__global__ __launch_bounds__(256)
void gemm_bt(const u16* __restrict__ A, const u16* __restrict__ Bw,
             const float* __restrict__ bias, void* __restrict__ Cout,
             u16* __restrict__ Vout, int K, int ldc)
{
    __shared__ u16 Ablk[128 * 64];
    __shared__ u16 Bblk[128 * 64];
    const int tid  = threadIdx.x;
    const int wave = tid >> 6;
    const int lane = tid & 63;
    const int quad = lane >> 4;
    const int l16  = lane & 15;
    const int m0 = blockIdx.y * 128;
    const int n0 = blockIdx.x * 128;
    const int mw = (wave & 1) * 64;
    const int nw = (wave >> 1) * 64;

    // staging: wave w stages rows [w*32, w*32+32) of A and B; 4 async ops of
    // 8 rows each. lane i -> row r8=i>>3, physical kg slot i&7 holds logical
    // kg = (i&7) ^ r8  (XOR swizzle so fragment reads are bank-conflict-free)
    const int r8 = lane >> 3;
    const int kgs = ((lane & 7) ^ r8) * 8;          // swizzled source col (u16)
    const u16* gA = A  + (size_t)(m0 + wave*32 + r8) * K + kgs;
    const u16* gB = Bw + (size_t)(n0 + wave*32 + r8) * K + kgs;
    u16* lA = Ablk + wave * 32 * 64;
    u16* lB = Bblk + wave * 32 * 64;

    floatx4 acc[4][4] = {};
    const int sw = l16 & 7;    // reader swizzle key (row & 7 == l16 & 7)

    for (int k0 = 0; k0 < K; k0 += 64) {
        __syncthreads();
        #pragma unroll
        for (int j = 0; j < 4; j++) {
            async_ld16(gA + k0 + (size_t)(j*8) * K, lA + j*8*64);
            async_ld16(gB + k0 + (size_t)(j*8) * K, lB + j*8*64);
        }
        __syncthreads();
        #pragma unroll
        for (int kk = 0; kk < 2; kk++) {
            short8 af[4], bfr[4];
            #pragma unroll
            for (int mt = 0; mt < 4; mt++)
                af[mt] = *(const short8*)(Ablk + (mw + mt*16 + l16)*64 + ((quad + 4*kk) ^ sw)*8);
            #pragma unroll
            for (int nt = 0; nt < 4; nt++)
                bfr[nt] = *(const short8*)(Bblk + (nw + nt*16 + l16)*64 + ((quad + 4*kk) ^ sw)*8);
            #pragma unroll
            for (int mt = 0; mt < 4; mt++)
                #pragma unroll
                for (int nt = 0; nt < 4; nt++)
                    acc[mt][nt] = __builtin_amdgcn_mfma_f32_16x16x32_bf16(af[mt], bfr[nt], acc[mt][nt], 0, 0, 0);
        }
    }

    // epilogue: C layout col=lane&15, row=quad*4+reg
    if (MODE == 1 && n0 >= LDQK) {
        // V block: write transposed vt[bh][d][t], 4 consecutive t packed (8B)
        const int nv = n0 + nw - LDQK + 0;          // base of this wave's n
        const int b  = m0 >> 9;
        #pragma unroll
        for (int nt = 0; nt < 4; nt++) {
            const int n  = nv + nt*16 + l16;        // 0..767
            const int hh = n >> 6, d = n & 63;
            const float bv = bias[LDQK + n];
            u16* vp = Vout + ((size_t)(b*NHEAD + hh) * HDIM + d) * TSEQ;
            #pragma unroll
            for (int mt = 0; mt < 4; mt++) {
                const int t0 = (m0 & 511) + mw + mt*16 + quad*4;
                u16 pack[4];
                #pragma unroll
                for (int r = 0; r < 4; r++) pack[r] = f2bf(acc[mt][nt][r] + bv);
                *(uint2*)(vp + t0) = *(const uint2*)pack;
            }
        }
    } else {
        #pragma unroll
        for (int nt = 0; nt < 4; nt++) {
            const int n = n0 + nw + nt*16 + l16;
            const float bv = bias[n];
            #pragma unroll
            for (int mt = 0; mt < 4; mt++) {
                #pragma unroll
                for (int r = 0; r < 4; r++) {
                    const int m = m0 + mw + mt*16 + quad*4 + r;
                    const float v = acc[mt][nt][r] + bv;
                    if (MODE == 1) ((u16*)Cout)[(size_t)m * ldc + n] = f2bf(v);
                    else           ((float*)Cout)[(size_t)m * ldc + n] = v;
                }
            }
        }
    }
}

// ---------------------------------------------------------------------------
// Attention: wave-independent, 32 q-rows/wave, explicit K/V register
// ping-pong double-buffering. qk[8192][1536] bf16 (q 0..767, k 768..1535),
// vt[bh][d][t] bf16 from the QKV GEMM's transposed-V epilogue.
// ---------------------------------------------------------------------------
#define PSTRIDE 40   // u16; 80 B rows: 16B-aligned b128 reads, 2-way-free writes

__global__ __launch_bounds__(256, 3)
void attn_kernel(const u16* __restrict__ qk, const u16* __restrict__ vt,
                 const int* __restrict__ mask, u16* __restrict__ attn_out)
{
    __shared__ float maskadd[TSEQ];
    __shared__ u16 Pbuf[4][2][16 * PSTRIDE];

    const int qt = blockIdx.x;        // 0..3 (128 q rows per block)
    const int bh = blockIdx.y;        // 0..191
    const int b = bh / NHEAD, h = bh - b * NHEAD;
    const int tid  = threadIdx.x;
    const int wave = tid >> 6;
    const int lane = tid & 63;
    const int quad = lane >> 4;
    const int l16  = lane & 15;

    for (int i = tid; i < TSEQ; i += 256)
        maskadd[i] = (mask[b*TSEQ + i] == 0) ? -1e9f : 0.0f;
    __syncthreads();   // the only block-wide barrier

    const size_t btok = (size_t)b * TSEQ;
    const int q0 = qt * 128 + wave * 32;

    // Q fragments for 2 row-tiles: A[m=l16][k=quad*8+j], two K-halves of HDIM
    short8 qf[2][2];
    #pragma unroll
    for (int m = 0; m < 2; m++) {
        const u16* qp = qk + (btok + q0 + m*16 + l16) * LDQK + h*HDIM + quad*8;
        qf[m][0] = *(const short8*)qp;
        qf[m][1] = *(const short8*)(qp + 32);
    }

    const u16* kbase = qk + btok * LDQK + H + h*HDIM + quad*8;
    const u16* vbase = vt + (size_t)bh * HDIM * TSEQ + quad*8;

    floatx4 o[2][4] = {};              // 2 x (16q x 64d), C-layout
    float lsum[2][4] = {};

    auto loadKV = [&](int kb, short8* kf, short8* vf) {
        const u16* kp0 = kbase + (size_t)(kb + l16) * LDQK;
        const u16* kp1 = kbase + (size_t)(kb + 16 + l16) * LDQK;
        kf[0] = *(const short8*)kp0;
        kf[1] = *(const short8*)(kp0 + 32);
        kf[2] = *(const short8*)kp1;
        kf[3] = *(const short8*)(kp1 + 32);
        #pragma unroll
        for (int d = 0; d < 4; d++)
            vf[d] = *(const short8*)(vbase + (size_t)(d*16 + l16) * TSEQ + kb);
    };

    auto compute = [&](int kb, const short8* kf, const short8* vf) {
        floatx4 s[2][2];
        #pragma unroll
        for (int m = 0; m < 2; m++)
            #pragma unroll
            for (int t = 0; t < 2; t++) {
                floatx4 acc = {0.f, 0.f, 0.f, 0.f};
                acc = __builtin_amdgcn_mfma_f32_16x16x32_bf16(qf[m][0], kf[t*2+0], acc, 0, 0, 0);
                acc = __builtin_amdgcn_mfma_f32_16x16x32_bf16(qf[m][1], kf[t*2+1], acc, 0, 0, 0);
                s[m][t] = acc;
            }
        const float m0 = maskadd[kb + l16];
        const float m1 = maskadd[kb + 16 + l16];
        #pragma unroll
        for (int m = 0; m < 2; m++) {
            u16* Pw = Pbuf[wave][m];
            #pragma unroll
            for (int r = 0; r < 4; r++) {
                const float p0 = __expf(s[m][0][r] * 0.125f + m0);
                const float p1 = __expf(s[m][1][r] * 0.125f + m1);
                lsum[m][r] += p0 + p1;
                Pw[(quad*4 + r) * PSTRIDE + l16]      = f2bf(p0);
                Pw[(quad*4 + r) * PSTRIDE + 16 + l16] = f2bf(p1);
            }
        }
        #pragma unroll
        for (int m = 0; m < 2; m++) {
            const short8 pa = *(const short8*)(Pbuf[wave][m] + l16 * PSTRIDE + quad*8);
            #pragma unroll
            for (int d = 0; d < 4; d++)
                o[m][d] = __builtin_amdgcn_mfma_f32_16x16x32_bf16(pa, vf[d], o[m][d], 0, 0, 0);
        }
    };

    short8 kA[4], vA[4], kB[4], vB[4];
    loadKV(0, kA, vA);
    for (int kb = 0; kb < TSEQ - 64; kb += 64) {
        loadKV(kb + 32, kB, vB);       // prefetch while computing on A
        compute(kb, kA, vA);
        loadKV(kb + 64, kA, vA);       // prefetch while computing on B
        compute(kb + 32, kB, vB);
    }
    loadKV(TSEQ - 32, kB, vB);
    compute(TSEQ - 64, kA, vA);
    compute(TSEQ - 32, kB, vB);

    #pragma unroll
    for (int m = 0; m < 2; m++) {
        float inv[4];
        #pragma unroll
        for (int r = 0; r < 4; r++) {
            float l = lsum[m][r];
            l += __shfl_xor(l, 1);
            l += __shfl_xor(l, 2);
            l += __shfl_xor(l, 4);
            l += __shfl_xor(l, 8);
            inv[r] = 1.0f / l;
        }
        #pragma unroll
        for (int d = 0; d < 4; d++)
            #pragma unroll
            for (int r = 0; r < 4; r++) {
                const int q = q0 + m*16 + quad*4 + r;
                attn_out[(btok + q) * H + h*HDIM + d*16 + l16] = f2bf(o[m][d][r] * inv[r]);
            }
    }
}

// ---------------------------------------------------------------------------
extern "C" void kernel_launch(void* const* d_in, const int* in_sizes, int n_in,
                              void* d_out, int out_size, void* d_ws, size_t ws_size,
                              hipStream_t stream)
{
    const float* x   = (const float*)d_in[0];
    const int* mask  = (const int*)d_in[1];
    const float* Wq  = (const float*)d_in[2];
    const float* bq  = (const float*)d_in[3];
    const float* Aq  = (const float*)d_in[4];
    const float* Bq  = (const float*)d_in[5];
    const float* Wk  = (const float*)d_in[6];
    const float* bk  = (const float*)d_in[7];
    const float* Wv  = (const float*)d_in[8];
    const float* bv  = (const float*)d_in[9];
    const float* Av  = (const float*)d_in[10];
    const float* Bv  = (const float*)d_in[11];
    const float* Wo  = (const float*)d_in[12];
    const float* bo  = (const float*)d_in[13];

    char* ws = (char*)d_ws;
    u16*   xb      = (u16*)  (ws);                 // 12,582,912 B
    u16*   Wall    = (u16*)  (ws + 12582912);      //  3,538,944 B
    u16*   Wobf    = (u16*)  (ws + 16121856);      //  1,179,648 B
    float* biasall = (float*)(ws + 17301504);      //      9,216 B
    u16*   qk      = (u16*)  (ws + 17310720);      // 25,165,824 B
    u16*   vt      = (u16*)  (ws + 42476544);      // 12,582,912 B
    u16*   attn_o  = (u16*)  (ws + 55059456);      // 12,582,912 B (end 67,642,368)

    prep_weights<<<(4*H*H)/256, 256, 0, stream>>>(Wq, bq, Aq, Bq, Wk, bk, Wv, bv,
                                                  Av, Bv, Wo, Wall, Wobf, biasall);
    cvt_x_kernel<<<(BT*H)/1024, 256, 0, stream>>>(x, xb);
    gemm_bt<1><<<dim3(C3/128, BT/128), 256, 0, stream>>>(xb, Wall, biasall, qk, vt, H, LDQK);
    attn_kernel<<<dim3(TSEQ/128, BATCH*NHEAD), 256, 0, stream>>>(qk, vt, mask, attn_o);
    gemm_bt<0><<<dim3(H/128, BT/128), 256, 0, stream>>>(attn_o, Wobf, bo, d_out, nullptr, H, H);
}

// Round 5
// 223.878 us; speedup vs baseline: 1.3369x; 1.0208x over previous
//
#include <hip/hip_runtime.h>
#include <stdint.h>

#define H 768
#define NHEAD 12
#define HDIM 64
#define BATCH 16
#define TSEQ 512
#define BT (BATCH*TSEQ)      // 8192 tokens
#define C3 (3*H)             // 2304
#define LDQK 1536            // packed Q,K row stride

typedef __attribute__((ext_vector_type(8))) short short8;
typedef __attribute__((ext_vector_type(4))) float floatx4;
typedef unsigned short u16;

__device__ __forceinline__ u16 f2bf(float f) {
    union { float f; unsigned int u; } v; v.f = f;
    unsigned int u = v.u;
    return (u16)((u + 0x7FFFu + ((u >> 16) & 1u)) >> 16);
}

// async global->LDS, 16B per lane; LDS dest = wave-uniform base + lane*16
__device__ __forceinline__ void async_ld16(const void* g, void* l) {
    __builtin_amdgcn_global_load_lds((__attribute__((address_space(1))) void*)g,
                                     (__attribute__((address_space(3))) void*)l,
                                     16, 0, 0);
}

// ---------------------------------------------------------------------------
// Prep: Wall[2304][768] = [Wq + 2*Bq@Aq ; Wk ; Wv + 2*Bv@Av] as bf16,
//       Wobf[768][768] = Wo bf16, bias_all[2304] fp32.
// ---------------------------------------------------------------------------
__global__ void prep_weights(const float* __restrict__ Wq, const float* __restrict__ bq,
                             const float* __restrict__ Aq, const float* __restrict__ Bq,
                             const float* __restrict__ Wk, const float* __restrict__ bk,
                             const float* __restrict__ Wv, const float* __restrict__ bv,
                             const float* __restrict__ Av, const float* __restrict__ Bv,
                             const float* __restrict__ Wo,
                             u16* __restrict__ Wall, u16* __restrict__ Wobf,
                             float* __restrict__ bias_all)
{
    const int idx = blockIdx.x * 256 + threadIdx.x;   // < 4*H*H
    const int r = idx / H;
    const int c = idx - r * H;
    if (r < H) {
        float v = Wq[idx] + 2.0f * (Bq[r*4+0]*Aq[c] + Bq[r*4+1]*Aq[H+c] +
                                    Bq[r*4+2]*Aq[2*H+c] + Bq[r*4+3]*Aq[3*H+c]);
        Wall[idx] = f2bf(v);
    } else if (r < 2*H) {
        Wall[idx] = f2bf(Wk[idx - H*H]);
    } else if (r < 3*H) {
        const int rr = r - 2*H;
        float v = Wv[rr*H + c] + 2.0f * (Bv[rr*4+0]*Av[c] + Bv[rr*4+1]*Av[H+c] +
                                         Bv[rr*4+2]*Av[2*H+c] + Bv[rr*4+3]*Av[3*H+c]);
        Wall[idx] = f2bf(v);
    } else {
        Wobf[idx - 3*H*H] = f2bf(Wo[idx - 3*H*H]);
    }
    if (idx < C3) {
        bias_all[idx] = (idx < H) ? bq[idx] : (idx < 2*H ? bk[idx - H] : bv[idx - 2*H]);
    }
}

__global__ void cvt_x_kernel(const float* __restrict__ x, u16* __restrict__ xb)
{
    const int i = (blockIdx.x * 256 + threadIdx.x) * 4;
    const float4 v = *(const float4*)(x + i);
    u16 o[4] = { f2bf(v.x), f2bf(v.y), f2bf(v.z), f2bf(v.w) };
    *(uint2*)(xb + i) = *(const uint2*)o;
}

// ---------------------------------------------------------------------------
// GEMM: C[M][N] = A[M][K] * B[N][K]^T + bias[N]   (A,B bf16, acc fp32)
// BK=32 (16 KB LDS -> r3-level occupancy) + XOR-swizzled LDS so the b128
// fragment reads are conflict-free (r4 verified SQ_LDS_BANK_CONFLICT=0).
// Swizzle: logical k-chunk g (8 u16) of row r stored at phys g ^ ((r>>1)&3).
// MODE 0: fp32 out, ldc=H.
// MODE 1: QKV — n<1536 -> bf16 qk[m][n] (ldc=1536); n>=1536 -> V transposed
//         into vt[bh][d][t] with packed 4xbf16 stores (t = m&511).
// ---------------------------------------------------------------------------
template<int MODE>
__global__ __launch_bounds__(256)
void gemm_bt(const u16* __restrict__ A, const u16* __restrict__ Bw,
             const float* __restrict__ bias, void* __restrict__ Cout,
             u16* __restrict__ Vout, int K, int ldc)
{
    __shared__ u16 Ablk[128 * 32];
    __shared__ u16 Bblk[128 * 32];
    const int tid  = threadIdx.x;
    const int wave = tid >> 6;
    const int lane = tid & 63;
    const int quad = lane >> 4;
    const int l16  = lane & 15;
    const int m0 = blockIdx.y * 128;
    const int n0 = blockIdx.x * 128;
    const int mw = (wave & 1) * 64;
    const int nw = (wave >> 1) * 64;

    // staging: wave stages rows [w*32, w*32+32); 2 async ops of 16 rows per
    // matrix. lane i -> row i>>2, phys chunk i&3 holds logical (i&3)^((i>>3)&3)
    const int srow = lane >> 2;
    const int scol = ((lane & 3) ^ ((lane >> 3) & 3)) * 8;
    const u16* gA = A  + (size_t)(m0 + wave*32 + srow) * K + scol;
    const u16* gB = Bw + (size_t)(n0 + wave*32 + srow) * K + scol;
    u16* lA = Ablk + wave * 32 * 32;
    u16* lB = Bblk + wave * 32 * 32;

    floatx4 acc[4][4] = {};
    const int rsw = ((l16 >> 1) & 3);   // reader swizzle: (row>>1)&3 == (l16>>1)&3

    for (int k0 = 0; k0 < K; k0 += 32) {
        __syncthreads();
        async_ld16(gA + k0,          lA);
        async_ld16(gA + k0 + 16*K,   lA + 16*32);
        async_ld16(gB + k0,          lB);
        async_ld16(gB + k0 + 16*K,   lB + 16*32);
        __syncthreads();
        short8 af[4], bfr[4];
        #pragma unroll
        for (int mt = 0; mt < 4; mt++)
            af[mt] = *(const short8*)(Ablk + (mw + mt*16 + l16)*32 + ((quad ^ rsw)*8));
        #pragma unroll
        for (int nt = 0; nt < 4; nt++)
            bfr[nt] = *(const short8*)(Bblk + (nw + nt*16 + l16)*32 + ((quad ^ rsw)*8));
        #pragma unroll
        for (int mt = 0; mt < 4; mt++)
            #pragma unroll
            for (int nt = 0; nt < 4; nt++)
                acc[mt][nt] = __builtin_amdgcn_mfma_f32_16x16x32_bf16(af[mt], bfr[nt], acc[mt][nt], 0, 0, 0);
    }

    // epilogue: C layout col=lane&15, row=quad*4+reg
    if (MODE == 1 && n0 >= LDQK) {
        const int nv = n0 + nw - LDQK;
        const int b  = m0 >> 9;
        #pragma unroll
        for (int nt = 0; nt < 4; nt++) {
            const int n  = nv + nt*16 + l16;        // 0..767
            const int hh = n >> 6, d = n & 63;
            const float bv = bias[LDQK + n];
            u16* vp = Vout + ((size_t)(b*NHEAD + hh) * HDIM + d) * TSEQ;
            #pragma unroll
            for (int mt = 0; mt < 4; mt++) {
                const int t0 = (m0 & 511) + mw + mt*16 + quad*4;
                u16 pack[4];
                #pragma unroll
                for (int r = 0; r < 4; r++) pack[r] = f2bf(acc[mt][nt][r] + bv);
                *(uint2*)(vp + t0) = *(const uint2*)pack;
            }
        }
    } else {
        #pragma unroll
        for (int nt = 0; nt < 4; nt++) {
            const int n = n0 + nw + nt*16 + l16;
            const float bv = bias[n];
            #pragma unroll
            for (int mt = 0; mt < 4; mt++) {
                #pragma unroll
                for (int r = 0; r < 4; r++) {
                    const int m = m0 + mw + mt*16 + quad*4 + r;
                    const float v = acc[mt][nt][r] + bv;
                    if (MODE == 1) ((u16*)Cout)[(size_t)m * ldc + n] = f2bf(v);
                    else           ((float*)Cout)[(size_t)m * ldc + n] = v;
                }
            }
        }
    }
}

// ---------------------------------------------------------------------------
// Attention v4: block-shared double-buffered LDS K/V staging (4x traffic cut
// vs wave-private global frag loads), m97-style 1-barrier/iter loop, XOR
// swizzled LDS so all fragment reads are conflict-free b128.
// Block = (b,h, 128 q rows); wave owns 32 q rows (2 m-tiles).
// ---------------------------------------------------------------------------
#define PSTRIDE 40   // u16; 80 B rows: conflict-free writes + b128 reads

__global__ __launch_bounds__(256)
void attn_kernel(const u16* __restrict__ qk, const u16* __restrict__ vt,
                 const int* __restrict__ mask, u16* __restrict__ attn_out)
{
    __shared__ float maskadd[TSEQ];                 // 2 KB
    __shared__ u16 Kbuf[2][32 * 64];                // 8 KB  [key][d], swizzled
    __shared__ u16 Vbuf[2][64 * 32];                // 8 KB  [d][key], swizzled
    __shared__ u16 Pbuf[4][2][16 * PSTRIDE];        // 10 KB

    const int qt = blockIdx.x;        // 0..3 (128 q rows per block)
    const int bh = blockIdx.y;        // 0..191
    const int b = bh / NHEAD, h = bh - b * NHEAD;
    const int tid  = threadIdx.x;
    const int wave = tid >> 6;
    const int lane = tid & 63;
    const int quad = lane >> 4;
    const int l16  = lane & 15;

    for (int i = tid; i < TSEQ; i += 256)
        maskadd[i] = (mask[b*TSEQ + i] == 0) ? -1e9f : 0.0f;

    const size_t btok = (size_t)b * TSEQ;
    const int q0 = qt * 128 + wave * 32;

    // Q fragments for 2 row-tiles: A[m=l16][k=quad*8+j], two d-halves
    short8 qf[2][2];
    #pragma unroll
    for (int m = 0; m < 2; m++) {
        const u16* qp = qk + (btok + q0 + m*16 + l16) * LDQK + h*HDIM + quad*8;
        qf[m][0] = *(const short8*)qp;
        qf[m][1] = *(const short8*)(qp + 32);
    }

    const u16* kglob = qk + btok * LDQK + H + h*HDIM;   // K rows, stride LDQK
    const u16* vglob = vt + (size_t)bh * HDIM * TSEQ;   // V^T rows, stride TSEQ

    // stage 32 keys into buf pp: wave w -> K rows [w*8,w*8+8), V^T d-rows [w*16,w*16+16)
    auto stage = [&](int kb, int pp) {
        {   // K[key][d]: lane i -> key kb+w*8+(i>>3), phys chunk i&7 = logical ^ (key&7)
            const int r = lane >> 3;
            const int g = (lane & 7) ^ r;               // key&7 == r (w*8 multiple of 8)
            async_ld16(kglob + (size_t)(kb + wave*8 + r) * LDQK + g*8,
                       &Kbuf[pp][wave*8*64]);
        }
        {   // V^T[d][key]: lane i -> d w*16+(i>>2), phys chunk i&3 = logical ^ ((d>>1)&3)
            const int dr = lane >> 2;
            const int g  = (lane & 3) ^ ((dr >> 1) & 3);
            async_ld16(vglob + (size_t)(wave*16 + dr) * TSEQ + kb + g*8,
                       &Vbuf[pp][wave*16*32]);
        }
    };

    floatx4 o[2][4] = {};              // 2 x (16q x 64d), C-layout
    float lsum[2][4] = {};

    auto compute = [&](int kb, int pp) {
        const u16* Kb_ = Kbuf[pp];
        const u16* Vb_ = Vbuf[pp];
        // K frags: subtile t (keys t*16+l16), d-half h2 -> chunk (h2*4+quad)^(l16&7)
        short8 kf[2][2];
        #pragma unroll
        for (int t = 0; t < 2; t++)
            #pragma unroll
            for (int h2 = 0; h2 < 2; h2++)
                kf[t][h2] = *(const short8*)(Kb_ + (t*16 + l16)*64 + (((h2*4 + quad) ^ (l16 & 7))*8));
        // V frags: d-tile dt (d = dt*16+l16), chunk quad^((l16>>1)&3)
        short8 vf[4];
        #pragma unroll
        for (int dt = 0; dt < 4; dt++)
            vf[dt] = *(const short8*)(Vb_ + (dt*16 + l16)*32 + ((quad ^ ((l16 >> 1) & 3))*8));

        floatx4 s[2][2];
        #pragma unroll
        for (int m = 0; m < 2; m++)
            #pragma unroll
            for (int t = 0; t < 2; t++) {
                floatx4 acc = {0.f, 0.f, 0.f, 0.f};
                acc = __builtin_amdgcn_mfma_f32_16x16x32_bf16(qf[m][0], kf[t][0], acc, 0, 0, 0);
                acc = __builtin_amdgcn_mfma_f32_16x16x32_bf16(qf[m][1], kf[t][1], acc, 0, 0, 0);
                s[m][t] = acc;
            }
        const float m0 = maskadd[kb + l16];
        const float m1 = maskadd[kb + 16 + l16];
        #pragma unroll
        for (int m = 0; m < 2; m++) {
            u16* Pw = Pbuf[wave][m];
            #pragma unroll
            for (int r = 0; r < 4; r++) {
                const float p0 = __expf(s[m][0][r] * 0.125f + m0);
                const float p1 = __expf(s[m][1][r] * 0.125f + m1);
                lsum[m][r] += p0 + p1;
                Pw[(quad*4 + r) * PSTRIDE + l16]      = f2bf(p0);
                Pw[(quad*4 + r) * PSTRIDE + 16 + l16] = f2bf(p1);
            }
        }
        #pragma unroll
        for (int m = 0; m < 2; m++) {
            const short8 pa = *(const short8*)(Pbuf[wave][m] + l16 * PSTRIDE + quad*8);
            #pragma unroll
            for (int dt = 0; dt < 4; dt++)
                o[m][dt] = __builtin_amdgcn_mfma_f32_16x16x32_bf16(pa, vf[dt], o[m][dt], 0, 0, 0);
        }
    };

    stage(0, 0);
    for (int it = 0; it < 16; it++) {
        __syncthreads();               // drains asyncs -> buf[it&1] ready; readers of buf[(it+1)&1] done
        if (it < 15) stage((it + 1) * 32, (it + 1) & 1);   // prefetch overlaps compute
        compute(it * 32, it & 1);
    }

    #pragma unroll
    for (int m = 0; m < 2; m++) {
        float inv[4];
        #pragma unroll
        for (int r = 0; r < 4; r++) {
            float l = lsum[m][r];
            l += __shfl_xor(l, 1);
            l += __shfl_xor(l, 2);
            l += __shfl_xor(l, 4);
            l += __shfl_xor(l, 8);
            inv[r] = 1.0f / l;
        }
        #pragma unroll
        for (int dt = 0; dt < 4; dt++)
            #pragma unroll
            for (int r = 0; r < 4; r++) {
                const int q = q0 + m*16 + quad*4 + r;
                attn_out[(btok + q) * H + h*HDIM + dt*16 + l16] = f2bf(o[m][dt][r] * inv[r]);
            }
    }
}

// ---------------------------------------------------------------------------
extern "C" void kernel_launch(void* const* d_in, const int* in_sizes, int n_in,
                              void* d_out, int out_size, void* d_ws, size_t ws_size,
                              hipStream_t stream)
{
    const float* x   = (const float*)d_in[0];
    const int* mask  = (const int*)d_in[1];
    const float* Wq  = (const float*)d_in[2];
    const float* bq  = (const float*)d_in[3];
    const float* Aq  = (const float*)d_in[4];
    const float* Bq  = (const float*)d_in[5];
    const float* Wk  = (const float*)d_in[6];
    const float* bk  = (const float*)d_in[7];
    const float* Wv  = (const float*)d_in[8];
    const float* bv  = (const float*)d_in[9];
    const float* Av  = (const float*)d_in[10];
    const float* Bv  = (const float*)d_in[11];
    const float* Wo  = (const float*)d_in[12];
    const float* bo  = (const float*)d_in[13];

    char* ws = (char*)d_ws;
    u16*   xb      = (u16*)  (ws);                 // 12,582,912 B
    u16*   Wall    = (u16*)  (ws + 12582912);      //  3,538,944 B
    u16*   Wobf    = (u16*)  (ws + 16121856);      //  1,179,648 B
    float* biasall = (float*)(ws + 17301504);      //      9,216 B
    u16*   qk      = (u16*)  (ws + 17310720);      // 25,165,824 B
    u16*   vt      = (u16*)  (ws + 42476544);      // 12,582,912 B
    u16*   attn_o  = (u16*)  (ws + 55059456);      // 12,582,912 B (end 67,642,368)

    prep_weights<<<(4*H*H)/256, 256, 0, stream>>>(Wq, bq, Aq, Bq, Wk, bk, Wv, bv,
                                                  Av, Bv, Wo, Wall, Wobf, biasall);
    cvt_x_kernel<<<(BT*H)/1024, 256, 0, stream>>>(x, xb);
    gemm_bt<1><<<dim3(C3/128, BT/128), 256, 0, stream>>>(xb, Wall, biasall, qk, vt, H, LDQK);
    attn_kernel<<<dim3(TSEQ/128, BATCH*NHEAD), 256, 0, stream>>>(qk, vt, mask, attn_o);
    gemm_bt<0><<<dim3(H/128, BT/128), 256, 0, stream>>>(attn_o, Wobf, bo, d_out, nullptr, H, H);
}

// Round 6
// 221.348 us; speedup vs baseline: 1.3521x; 1.0114x over previous
//
#include <hip/hip_runtime.h>
#include <stdint.h>

#define H 768
#define NHEAD 12
#define HDIM 64
#define BATCH 16
#define TSEQ 512
#define BT (BATCH*TSEQ)      // 8192 tokens
#define C3 (3*H)             // 2304
#define LDQK 1536            // packed Q,K row stride

typedef __attribute__((ext_vector_type(8))) short short8;
typedef __attribute__((ext_vector_type(4))) float floatx4;
typedef unsigned short u16;

__device__ __forceinline__ u16 f2bf(float f) {
    union { float f; unsigned int u; } v; v.f = f;
    unsigned int u = v.u;
    return (u16)((u + 0x7FFFu + ((u >> 16) & 1u)) >> 16);
}

// async global->LDS, 16B per lane; LDS dest = wave-uniform base + lane*16
__device__ __forceinline__ void async_ld16(const void* g, void* l) {
    __builtin_amdgcn_global_load_lds((__attribute__((address_space(1))) void*)g,
                                     (__attribute__((address_space(3))) void*)l,
                                     16, 0, 0);
}

// ---------------------------------------------------------------------------
// Prep: Wall[2304][768] = [Wq + 2*Bq@Aq ; Wk ; Wv + 2*Bv@Av] as bf16,
//       Wobf[768][768] = Wo bf16, bias_all[2304] fp32.
// ---------------------------------------------------------------------------
__global__ void prep_weights(const float* __restrict__ Wq, const float* __restrict__ bq,
                             const float* __restrict__ Aq, const float* __restrict__ Bq,
                             const float* __restrict__ Wk, const float* __restrict__ bk,
                             const float* __restrict__ Wv, const float* __restrict__ bv,
                             const float* __restrict__ Av, const float* __restrict__ Bv,
                             const float* __restrict__ Wo,
                             u16* __restrict__ Wall, u16* __restrict__ Wobf,
                             float* __restrict__ bias_all)
{
    const int idx = blockIdx.x * 256 + threadIdx.x;   // < 4*H*H
    const int r = idx / H;
    const int c = idx - r * H;
    if (r < H) {
        float v = Wq[idx] + 2.0f * (Bq[r*4+0]*Aq[c] + Bq[r*4+1]*Aq[H+c] +
                                    Bq[r*4+2]*Aq[2*H+c] + Bq[r*4+3]*Aq[3*H+c]);
        Wall[idx] = f2bf(v);
    } else if (r < 2*H) {
        Wall[idx] = f2bf(Wk[idx - H*H]);
    } else if (r < 3*H) {
        const int rr = r - 2*H;
        float v = Wv[rr*H + c] + 2.0f * (Bv[rr*4+0]*Av[c] + Bv[rr*4+1]*Av[H+c] +
                                         Bv[rr*4+2]*Av[2*H+c] + Bv[rr*4+3]*Av[3*H+c]);
        Wall[idx] = f2bf(v);
    } else {
        Wobf[idx - 3*H*H] = f2bf(Wo[idx - 3*H*H]);
    }
    if (idx < C3) {
        bias_all[idx] = (idx < H) ? bq[idx] : (idx < 2*H ? bk[idx - H] : bv[idx - 2*H]);
    }
}

__global__ void cvt_x_kernel(const float* __restrict__ x, u16* __restrict__ xb)
{
    const int i = (blockIdx.x * 256 + threadIdx.x) * 4;
    const float4 v = *(const float4*)(x + i);
    u16 o[4] = { f2bf(v.x), f2bf(v.y), f2bf(v.z), f2bf(v.w) };
    *(uint2*)(xb + i) = *(const uint2*)o;
}

// ---------------------------------------------------------------------------
// GEMM: C[M][N] = A[M][K] * B[N][K]^T + bias[N]   (A,B bf16, acc fp32)
// LINEAR coalesced global_load_lds staging (r5 post-mortem: XOR-swizzled
// source addresses broke DMA coalescing, +41% dur; 8-way LDS read conflicts
// cost only ~10% — accept them). Single-barrier double-buffered pipeline:
// stage(it+1) issues after the barrier and drains one compute-phase later.
// TM = M-tile (128 or 64). MODE 0: fp32 out. MODE 1: QKV with V transposed
// into vt[bh][d][t].
// ---------------------------------------------------------------------------
template<int MODE, int TM>
__global__ __launch_bounds__(256)
void gemm_bt(const u16* __restrict__ A, const u16* __restrict__ Bw,
             const float* __restrict__ bias, void* __restrict__ Cout,
             u16* __restrict__ Vout, int K, int ldc)
{
    constexpr int MT = TM / 32;            // m-tiles per wave (4 or 2)
    __shared__ u16 Ablk[2][TM * 32];
    __shared__ u16 Bblk[2][128 * 32];
    const int tid  = threadIdx.x;
    const int wave = tid >> 6;
    const int lane = tid & 63;
    const int quad = lane >> 4;
    const int l16  = lane & 15;
    const int m0 = blockIdx.y * TM;
    const int n0 = blockIdx.x * 128;
    const int mw = (wave & 1) * (TM / 2);
    const int nw = (wave >> 1) * 64;

    // staging (linear): lane i -> row i>>2, k-chunk i&3 (16B); wave covers
    // A rows [wave*(TM/4), +TM/4) and B rows [wave*32, +32)
    const int srow = lane >> 2;
    const int scol = (lane & 3) * 8;
    const int arow0 = wave * (TM / 4);
    const u16* gA = A  + (size_t)(m0 + arow0 + srow) * K + scol;
    const u16* gB = Bw + (size_t)(n0 + wave*32 + srow) * K + scol;

    floatx4 acc[MT][4] = {};

    auto stage = [&](int k0, int pp) {
        u16* lA = Ablk[pp] + arow0 * 32;
        u16* lB = Bblk[pp] + wave * 32 * 32;
        async_ld16(gA + k0, lA);
        if (TM == 128) async_ld16(gA + k0 + 16*K, lA + 16*32);
        async_ld16(gB + k0, lB);
        async_ld16(gB + k0 + 16*K, lB + 16*32);
    };

    auto compute = [&](int pp) {
        short8 af[MT], bfr[4];
        #pragma unroll
        for (int mt = 0; mt < MT; mt++)
            af[mt] = *(const short8*)(Ablk[pp] + (mw + mt*16 + l16)*32 + quad*8);
        #pragma unroll
        for (int nt = 0; nt < 4; nt++)
            bfr[nt] = *(const short8*)(Bblk[pp] + (nw + nt*16 + l16)*32 + quad*8);
        #pragma unroll
        for (int mt = 0; mt < MT; mt++)
            #pragma unroll
            for (int nt = 0; nt < 4; nt++)
                acc[mt][nt] = __builtin_amdgcn_mfma_f32_16x16x32_bf16(af[mt], bfr[nt], acc[mt][nt], 0, 0, 0);
    };

    const int nIter = K >> 5;
    stage(0, 0);
    for (int it = 0; it < nIter; it++) {
        __syncthreads();               // drains stage(it) (issued 1 phase ago)
        if (it + 1 < nIter) stage((it + 1) * 32, (it + 1) & 1);
        compute(it & 1);
    }

    // epilogue: C layout col=lane&15, row=quad*4+reg
    if (MODE == 1 && n0 >= LDQK) {
        const int nv = n0 + nw - LDQK;
        const int b  = m0 >> 9;
        #pragma unroll
        for (int nt = 0; nt < 4; nt++) {
            const int n  = nv + nt*16 + l16;        // 0..767
            const int hh = n >> 6, d = n & 63;
            const float bv = bias[LDQK + n];
            u16* vp = Vout + ((size_t)(b*NHEAD + hh) * HDIM + d) * TSEQ;
            #pragma unroll
            for (int mt = 0; mt < MT; mt++) {
                const int t0 = (m0 & 511) + mw + mt*16 + quad*4;
                u16 pack[4];
                #pragma unroll
                for (int r = 0; r < 4; r++) pack[r] = f2bf(acc[mt][nt][r] + bv);
                *(uint2*)(vp + t0) = *(const uint2*)pack;
            }
        }
    } else {
        #pragma unroll
        for (int nt = 0; nt < 4; nt++) {
            const int n = n0 + nw + nt*16 + l16;
            const float bv = bias[n];
            #pragma unroll
            for (int mt = 0; mt < MT; mt++) {
                #pragma unroll
                for (int r = 0; r < 4; r++) {
                    const int m = m0 + mw + mt*16 + quad*4 + r;
                    const float v = acc[mt][nt][r] + bv;
                    if (MODE == 1) ((u16*)Cout)[(size_t)m * ldc + n] = f2bf(v);
                    else           ((float*)Cout)[(size_t)m * ldc + n] = v;
                }
            }
        }
    }
}

// ---------------------------------------------------------------------------
// Attention: block-shared double-buffered LDS K/V staging, 1 barrier/iter,
// XOR-swizzled LDS (required here: unswizzled K-frag reads would be 16-way
// conflicted; swizzled staging DMA cost accepted — attn is not top dispatch).
// Block = (b,h, 128 q rows); wave owns 32 q rows (2 m-tiles).
// ---------------------------------------------------------------------------
#define PSTRIDE 40   // u16; 80 B rows: conflict-free writes + b128 reads

__global__ __launch_bounds__(256)
void attn_kernel(const u16* __restrict__ qk, const u16* __restrict__ vt,
                 const int* __restrict__ mask, u16* __restrict__ attn_out)
{
    __shared__ float maskadd[TSEQ];                 // 2 KB
    __shared__ u16 Kbuf[2][32 * 64];                // 8 KB  [key][d], swizzled
    __shared__ u16 Vbuf[2][64 * 32];                // 8 KB  [d][key], swizzled
    __shared__ u16 Pbuf[4][2][16 * PSTRIDE];        // 10 KB

    const int qt = blockIdx.x;        // 0..3 (128 q rows per block)
    const int bh = blockIdx.y;        // 0..191
    const int b = bh / NHEAD, h = bh - b * NHEAD;
    const int tid  = threadIdx.x;
    const int wave = tid >> 6;
    const int lane = tid & 63;
    const int quad = lane >> 4;
    const int l16  = lane & 15;

    for (int i = tid; i < TSEQ; i += 256)
        maskadd[i] = (mask[b*TSEQ + i] == 0) ? -1e9f : 0.0f;

    const size_t btok = (size_t)b * TSEQ;
    const int q0 = qt * 128 + wave * 32;

    // Q fragments for 2 row-tiles: A[m=l16][k=quad*8+j], two d-halves
    short8 qf[2][2];
    #pragma unroll
    for (int m = 0; m < 2; m++) {
        const u16* qp = qk + (btok + q0 + m*16 + l16) * LDQK + h*HDIM + quad*8;
        qf[m][0] = *(const short8*)qp;
        qf[m][1] = *(const short8*)(qp + 32);
    }

    const u16* kglob = qk + btok * LDQK + H + h*HDIM;   // K rows, stride LDQK
    const u16* vglob = vt + (size_t)bh * HDIM * TSEQ;   // V^T rows, stride TSEQ

    auto stage = [&](int kb, int pp) {
        {   // K[key][d]: lane i -> key kb+w*8+(i>>3), phys chunk i&7 = logical ^ (key&7)
            const int r = lane >> 3;
            const int g = (lane & 7) ^ r;
            async_ld16(kglob + (size_t)(kb + wave*8 + r) * LDQK + g*8,
                       &Kbuf[pp][wave*8*64]);
        }
        {   // V^T[d][key]: lane i -> d w*16+(i>>2), phys chunk i&3 = logical ^ ((d>>1)&3)
            const int dr = lane >> 2;
            const int g  = (lane & 3) ^ ((dr >> 1) & 3);
            async_ld16(vglob + (size_t)(wave*16 + dr) * TSEQ + kb + g*8,
                       &Vbuf[pp][wave*16*32]);
        }
    };

    floatx4 o[2][4] = {};              // 2 x (16q x 64d), C-layout
    float lsum[2][4] = {};

    auto compute = [&](int kb, int pp) {
        const u16* Kb_ = Kbuf[pp];
        const u16* Vb_ = Vbuf[pp];
        short8 kf[2][2];
        #pragma unroll
        for (int t = 0; t < 2; t++)
            #pragma unroll
            for (int h2 = 0; h2 < 2; h2++)
                kf[t][h2] = *(const short8*)(Kb_ + (t*16 + l16)*64 + (((h2*4 + quad) ^ (l16 & 7))*8));
        short8 vf[4];
        #pragma unroll
        for (int dt = 0; dt < 4; dt++)
            vf[dt] = *(const short8*)(Vb_ + (dt*16 + l16)*32 + ((quad ^ ((l16 >> 1) & 3))*8));

        floatx4 s[2][2];
        #pragma unroll
        for (int m = 0; m < 2; m++)
            #pragma unroll
            for (int t = 0; t < 2; t++) {
                floatx4 acc = {0.f, 0.f, 0.f, 0.f};
                acc = __builtin_amdgcn_mfma_f32_16x16x32_bf16(qf[m][0], kf[t][0], acc, 0, 0, 0);
                acc = __builtin_amdgcn_mfma_f32_16x16x32_bf16(qf[m][1], kf[t][1], acc, 0, 0, 0);
                s[m][t] = acc;
            }
        const float m0 = maskadd[kb + l16];
        const float m1 = maskadd[kb + 16 + l16];
        #pragma unroll
        for (int m = 0; m < 2; m++) {
            u16* Pw = Pbuf[wave][m];
            #pragma unroll
            for (int r = 0; r < 4; r++) {
                const float p0 = __expf(s[m][0][r] * 0.125f + m0);
                const float p1 = __expf(s[m][1][r] * 0.125f + m1);
                lsum[m][r] += p0 + p1;
                Pw[(quad*4 + r) * PSTRIDE + l16]      = f2bf(p0);
                Pw[(quad*4 + r) * PSTRIDE + 16 + l16] = f2bf(p1);
            }
        }
        #pragma unroll
        for (int m = 0; m < 2; m++) {
            const short8 pa = *(const short8*)(Pbuf[wave][m] + l16 * PSTRIDE + quad*8);
            #pragma unroll
            for (int dt = 0; dt < 4; dt++)
                o[m][dt] = __builtin_amdgcn_mfma_f32_16x16x32_bf16(pa, vf[dt], o[m][dt], 0, 0, 0);
        }
    };

    stage(0, 0);
    for (int it = 0; it < 16; it++) {
        __syncthreads();
        if (it < 15) stage((it + 1) * 32, (it + 1) & 1);
        compute(it * 32, it & 1);
    }

    #pragma unroll
    for (int m = 0; m < 2; m++) {
        float inv[4];
        #pragma unroll
        for (int r = 0; r < 4; r++) {
            float l = lsum[m][r];
            l += __shfl_xor(l, 1);
            l += __shfl_xor(l, 2);
            l += __shfl_xor(l, 4);
            l += __shfl_xor(l, 8);
            inv[r] = 1.0f / l;
        }
        #pragma unroll
        for (int dt = 0; dt < 4; dt++)
            #pragma unroll
            for (int r = 0; r < 4; r++) {
                const int q = q0 + m*16 + quad*4 + r;
                attn_out[(btok + q) * H + h*HDIM + dt*16 + l16] = f2bf(o[m][dt][r] * inv[r]);
            }
    }
}

// ---------------------------------------------------------------------------
extern "C" void kernel_launch(void* const* d_in, const int* in_sizes, int n_in,
                              void* d_out, int out_size, void* d_ws, size_t ws_size,
                              hipStream_t stream)
{
    const float* x   = (const float*)d_in[0];
    const int* mask  = (const int*)d_in[1];
    const float* Wq  = (const float*)d_in[2];
    const float* bq  = (const float*)d_in[3];
    const float* Aq  = (const float*)d_in[4];
    const float* Bq  = (const float*)d_in[5];
    const float* Wk  = (const float*)d_in[6];
    const float* bk  = (const float*)d_in[7];
    const float* Wv  = (const float*)d_in[8];
    const float* bv  = (const float*)d_in[9];
    const float* Av  = (const float*)d_in[10];
    const float* Bv  = (const float*)d_in[11];
    const float* Wo  = (const float*)d_in[12];
    const float* bo  = (const float*)d_in[13];

    char* ws = (char*)d_ws;
    u16*   xb      = (u16*)  (ws);                 // 12,582,912 B
    u16*   Wall    = (u16*)  (ws + 12582912);      //  3,538,944 B
    u16*   Wobf    = (u16*)  (ws + 16121856);      //  1,179,648 B
    float* biasall = (float*)(ws + 17301504);      //      9,216 B
    u16*   qk      = (u16*)  (ws + 17310720);      // 25,165,824 B
    u16*   vt      = (u16*)  (ws + 42476544);      // 12,582,912 B
    u16*   attn_o  = (u16*)  (ws + 55059456);      // 12,582,912 B (end 67,642,368)

    prep_weights<<<(4*H*H)/256, 256, 0, stream>>>(Wq, bq, Aq, Bq, Wk, bk, Wv, bv,
                                                  Av, Bv, Wo, Wall, Wobf, biasall);
    cvt_x_kernel<<<(BT*H)/1024, 256, 0, stream>>>(x, xb);
    gemm_bt<1,128><<<dim3(C3/128, BT/128), 256, 0, stream>>>(xb, Wall, biasall, qk, vt, H, LDQK);
    attn_kernel<<<dim3(TSEQ/128, BATCH*NHEAD), 256, 0, stream>>>(qk, vt, mask, attn_o);
    gemm_bt<0,64><<<dim3(H/128, BT/64), 256, 0, stream>>>(attn_o, Wobf, bo, d_out, nullptr, H, H);
}